// Round 10
// baseline (120.397 us; speedup 1.0000x reference)
//
#include <hip/hip_runtime.h>
#include <hip/hip_bf16.h>
#include <stdint.h>

// ConstrastiveLoss2: loss = (sum_i lse_row(i) + sum_j lse_col(j) - 2*sum_i diag_i) / (2B)
// logits = tau * ftir @ raman^T, tau = min(exp(log_tau), 100), B=4096, D=512.
// R10: cast kernel DELETED. The gemm reads fp32 panels directly from d_in,
// converts to bf16 in-register during staging (ds_write_b128, XOR-swizzled
// layout identical to R7's verified one). Diag extracted from the MFMA acc of
// the 32 diagonal blocks (bf16 precision: loss error ~0.02 << 23.5 threshold).
// Dispatches: memset(8B) -> gemm -> combine.

typedef float f32x4 __attribute__((ext_vector_type(4)));
typedef __bf16 bf16x8 __attribute__((ext_vector_type(8)));

#define B_DIM 4096
#define D_DIM 512
#define NCHUNK 32   // partial chunks per row/col (one per 128-tile in the other dim)

// ---------------- fused GEMM + per-tile row/col (max, sumexp) partials ----------------
// 1024 blocks (XCD-swizzled); 4 waves in 2x2; wave computes 64x64 via 4x4 of
// 16x16x32 MFMA. BK=32, double-buffered; staging = fp32 load + cvt + ds_write.
__global__ __launch_bounds__(256, 3) void gemm_lse_kernel(
    const float* __restrict__ Af, const float* __restrict__ Bf,
    const float* __restrict__ log_tau,
    float* __restrict__ row_pmax, float* __restrict__ row_psum,
    float* __restrict__ col_pmax, float* __restrict__ col_psum,
    float* __restrict__ accg) {
  __shared__ char smem[34816];                 // 2 stages x (A 8KB + B 8KB); epilogue overlay
  // XCD swizzle: blk%8 ~ XCD id; each XCD gets an 8(bm) x 16(bn) cluster.
  const int blk = blockIdx.x;
  const int xcd = blk & 7, loc = blk >> 3;
  const int bm = (xcd & 3) * 8 + (loc & 7);
  const int bn = (xcd >> 2) * 16 + (loc >> 3);
  const int t = threadIdx.x;
  const int lane = t & 63;
  const int w = t >> 6;
  const int wm = (w >> 1) * 64, wn = (w & 1) * 64;
  const int q = lane >> 4, c16 = lane & 15;
  const int kbs = q ^ ((c16 >> 1) & 3);        // physical 16B-block for this lane (read side)

  f32x4 acc[4][4] = {};

  // staging: thread t -> LDS-tile row t>>1 (0..127), k-half t&1 (16 fp32 el = 4 float4)
  const int srow = t >> 1;
  const int sw   = (t >> 2) & 3;               // ((srow>>1)&3) write-side swizzle
  const int kb0  = (t & 1) * 2;                // first logical 8-el k-block of this half
  const float4* Ag0 = (const float4*)(Af + (size_t)(bm * 128 + srow) * D_DIM) + (t & 1) * 4;
  const float4* Bg0 = (const float4*)(Bf + (size_t)(bn * 128 + srow) * D_DIM) + (t & 1) * 4;
  const int ldsA = srow * 64 /*bytes*/;        // row stride 32 el * 2B

  float4 a0, a1, a2, a3, b0, b1, b2, b3;

  #define LOADS(kt)                                                           \
    do {                                                                      \
      const float4* ag = Ag0 + (kt) * 8;                                      \
      const float4* bg = Bg0 + (kt) * 8;                                      \
      a0 = ag[0]; a1 = ag[1]; a2 = ag[2]; a3 = ag[3];                         \
      b0 = bg[0]; b1 = bg[1]; b2 = bg[2]; b3 = bg[3];                         \
    } while (0)

  #define COMMIT(p)                                                           \
    do {                                                                      \
      bf16x8 pa0, pa1, pb0, pb1;                                              \
      pa0[0]=(__bf16)a0.x; pa0[1]=(__bf16)a0.y; pa0[2]=(__bf16)a0.z; pa0[3]=(__bf16)a0.w; \
      pa0[4]=(__bf16)a1.x; pa0[5]=(__bf16)a1.y; pa0[6]=(__bf16)a1.z; pa0[7]=(__bf16)a1.w; \
      pa1[0]=(__bf16)a2.x; pa1[1]=(__bf16)a2.y; pa1[2]=(__bf16)a2.z; pa1[3]=(__bf16)a2.w; \
      pa1[4]=(__bf16)a3.x; pa1[5]=(__bf16)a3.y; pa1[6]=(__bf16)a3.z; pa1[7]=(__bf16)a3.w; \
      pb0[0]=(__bf16)b0.x; pb0[1]=(__bf16)b0.y; pb0[2]=(__bf16)b0.z; pb0[3]=(__bf16)b0.w; \
      pb0[4]=(__bf16)b1.x; pb0[5]=(__bf16)b1.y; pb0[6]=(__bf16)b1.z; pb0[7]=(__bf16)b1.w; \
      pb1[0]=(__bf16)b2.x; pb1[1]=(__bf16)b2.y; pb1[2]=(__bf16)b2.z; pb1[3]=(__bf16)b2.w; \
      pb1[4]=(__bf16)b3.x; pb1[5]=(__bf16)b3.y; pb1[6]=(__bf16)b3.z; pb1[7]=(__bf16)b3.w; \
      char* base = smem + (p) * 16384;                                        \
      *(bf16x8*)(base + ldsA + ((kb0 ^ sw)) * 16)        = pa0;               \
      *(bf16x8*)(base + ldsA + (((kb0 + 1) ^ sw)) * 16)  = pa1;               \
      *(bf16x8*)(base + 8192 + ldsA + ((kb0 ^ sw)) * 16)       = pb0;         \
      *(bf16x8*)(base + 8192 + ldsA + (((kb0 + 1) ^ sw)) * 16) = pb1;         \
    } while (0)

  #define COMPUTE(p)                                                          \
    do {                                                                      \
      const char* Ab = smem + (p) * 16384;                                    \
      const char* Bb = Ab + 8192;                                             \
      bf16x8 af[4], bfr[4];                                                   \
      _Pragma("unroll")                                                       \
      for (int mi = 0; mi < 4; ++mi)                                          \
        af[mi] = *(const bf16x8*)(Ab + (wm + mi * 16 + c16) * 64 + kbs * 16); \
      _Pragma("unroll")                                                       \
      for (int ni = 0; ni < 4; ++ni)                                          \
        bfr[ni] = *(const bf16x8*)(Bb + (wn + ni * 16 + c16) * 64 + kbs * 16);\
      _Pragma("unroll")                                                       \
      for (int mi = 0; mi < 4; ++mi)                                          \
        _Pragma("unroll")                                                     \
        for (int ni = 0; ni < 4; ++ni)                                        \
          acc[mi][ni] = __builtin_amdgcn_mfma_f32_16x16x32_bf16(              \
              af[mi], bfr[ni], acc[mi][ni], 0, 0, 0);                         \
    } while (0)

  LOADS(0);
  COMMIT(0);
  for (int kt = 0; kt < 16; ++kt) {
    __syncthreads();                           // stage kt's ds_writes visible to all waves
    if (kt < 15) LOADS(kt + 1);                // global latency hidden by COMPUTE below
    COMPUTE(kt & 1);
    if (kt < 15) COMMIT((kt + 1) & 1);         // writes buf read 2 iters ago: all readers done
  }
  __syncthreads();                             // all compute reads done before smem reuse
  #undef LOADS
  #undef COMMIT
  #undef COMPUTE

  const float tau = fminf(__expf(log_tau[0]), 100.0f);
  #pragma unroll
  for (int mi = 0; mi < 4; ++mi)
    #pragma unroll
    for (int ni = 0; ni < 4; ++ni)
      acc[mi][ni] *= tau;

  // C layout (m89): col = wn + ni*16 + c16, row = wm + mi*16 + q*4 + r.
  // ---- diag extraction: diagonal blocks, waves 0/3, lanes with c16 == 4q+r ----
  if (bm == bn && (w == 0 || w == 3)) {
    float dsum = 0.f;
    int r = c16 - (q << 2);
    #pragma unroll
    for (int rr = 0; rr < 4; ++rr)
      if (rr == r) {
        #pragma unroll
        for (int mi = 0; mi < 4; ++mi) dsum += acc[mi][mi][rr];
      }
    #pragma unroll
    for (int off = 1; off < 64; off <<= 1) dsum += __shfl_xor(dsum, off);
    if (lane == 0) atomicAdd(accg, -2.0f * dsum);   // acc pre-zeroed by memset
  }

  // ---- rows phase 1: per-lane reduce over 4 ni values, scatter to rowbuf[128][33] ----
  float2* rbuf = (float2*)smem;
  #pragma unroll
  for (int mi = 0; mi < 4; ++mi)
    #pragma unroll
    for (int r = 0; r < 4; ++r) {
      float v0 = acc[mi][0][r], v1 = acc[mi][1][r], v2 = acc[mi][2][r], v3 = acc[mi][3][r];
      float m = fmaxf(fmaxf(v0, v1), fmaxf(v2, v3));
      float s = __expf(v0 - m) + __expf(v1 - m) + __expf(v2 - m) + __expf(v3 - m);
      int R = wm + mi * 16 + q * 4 + r;
      rbuf[R * 33 + (w & 1) * 16 + c16] = make_float2(m, s);
    }
  __syncthreads();
  // ---- rows phase 2: thread t<128 combines row t's 32 partials ----
  if (t < 128) {
    float M = rbuf[t * 33].x;
    #pragma unroll
    for (int x = 1; x < 32; ++x) M = fmaxf(M, rbuf[t * 33 + x].x);
    float S = 0.f;
    #pragma unroll
    for (int x = 0; x < 32; ++x) { float2 p = rbuf[t * 33 + x]; S += p.y * __expf(p.x - M); }
    row_pmax[bn * B_DIM + bm * 128 + t] = M;   // chunk-major: coalesced here AND in combine
    row_psum[bn * B_DIM + bm * 128 + t] = S;
  }
  __syncthreads();
  // ---- cols phase 1: per-lane reduce over 16 (mi,r) values, scatter to cbuf[128][9] ----
  float2* cbuf = (float2*)smem;
  #pragma unroll
  for (int ni = 0; ni < 4; ++ni) {
    float m = -3.0e38f;
    #pragma unroll
    for (int mi = 0; mi < 4; ++mi)
      #pragma unroll
      for (int r = 0; r < 4; ++r) m = fmaxf(m, acc[mi][ni][r]);
    float s = 0.f;
    #pragma unroll
    for (int mi = 0; mi < 4; ++mi)
      #pragma unroll
      for (int r = 0; r < 4; ++r) s += __expf(acc[mi][ni][r] - m);
    int C = wn + ni * 16 + c16;
    cbuf[C * 9 + (w >> 1) * 4 + q] = make_float2(m, s);
  }
  __syncthreads();
  // ---- cols phase 2: thread t<128 combines col t's 8 partials ----
  if (t < 128) {
    float M = cbuf[t * 9].x;
    #pragma unroll
    for (int y = 1; y < 8; ++y) M = fmaxf(M, cbuf[t * 9 + y].x);
    float S = 0.f;
    #pragma unroll
    for (int y = 0; y < 8; ++y) { float2 p = cbuf[t * 9 + y]; S += p.y * __expf(p.x - M); }
    col_pmax[bm * B_DIM + bn * 128 + t] = M;
    col_psum[bm * B_DIM + bn * 128 + t] = S;
  }
}

// ---------------- combine: thread per item; last block (counter) writes d_out ----------------
__global__ __launch_bounds__(256) void combine_kernel(
    const float* __restrict__ row_pmax, const float* __restrict__ row_psum,
    const float* __restrict__ col_pmax, const float* __restrict__ col_psum,
    float* __restrict__ acc, unsigned* __restrict__ counter,
    float* __restrict__ out) {
  const int t = threadIdx.x;
  const int item = blockIdx.x * 256 + t;       // 0..4095 rows, 4096..8191 cols
  const float* pm; const float* ps; int i;
  if (item < B_DIM) { pm = row_pmax; ps = row_psum; i = item; }
  else              { pm = col_pmax; ps = col_psum; i = item - B_DIM; }
  float M = pm[i];
  #pragma unroll
  for (int k = 1; k < NCHUNK; ++k) M = fmaxf(M, pm[k * B_DIM + i]);
  float S = 0.f;
  #pragma unroll
  for (int k = 0; k < NCHUNK; ++k) S += ps[k * B_DIM + i] * __expf(pm[k * B_DIM + i] - M);
  float local = M + __logf(S);
  #pragma unroll
  for (int off = 1; off < 64; off <<= 1) local += __shfl_xor(local, off);
  __shared__ float red[4];
  int w = t >> 6, lane = t & 63;
  if (lane == 0) red[w] = local;
  __syncthreads();
  if (t == 0) {
    atomicAdd(acc, red[0] + red[1] + red[2] + red[3]);
    __threadfence();
    unsigned old = atomicAdd(counter, 1u);
    if (old == 31u) {                          // last of the 32 blocks: finalize
      float v = atomicAdd(acc, 0.0f);          // coherent read after all adds (incl. diag)
      out[0] = v * (1.0f / 8192.0f);
    }
  }
}

// ---------------- launch ----------------
extern "C" void kernel_launch(void* const* d_in, const int* in_sizes, int n_in,
                              void* d_out, int out_size, void* d_ws, size_t ws_size,
                              hipStream_t stream) {
  const float* ftir    = (const float*)d_in[0];
  const float* raman   = (const float*)d_in[1];
  // d_in[2] = labels (int64) — unused by the reference output
  const float* log_tau = (const float*)d_in[3];
  float* out = (float*)d_out;

  char* ws = (char*)d_ws;
  // ws layout: row_pmax 512K | row_psum 512K | col_pmax 512K | col_psum 512K |
  //            acc 4B | counter 4B
  float* row_pmax = (float*)(ws);
  float* row_psum = (float*)(ws + (512u << 10));
  float* col_pmax = (float*)(ws + (1024u << 10));
  float* col_psum = (float*)(ws + (1536u << 10));
  float* acc      = (float*)(ws + (2048u << 10));
  unsigned* cnt   = (unsigned*)(ws + (2048u << 10) + 4);

  hipMemsetAsync(acc, 0, 8, stream);           // zeroes acc + counter
  gemm_lse_kernel<<<1024, 256, 0, stream>>>(ftir, raman, log_tau,
                                            row_pmax, row_psum, col_pmax, col_psum, acc);
  combine_kernel<<<32, 256, 0, stream>>>(row_pmax, row_psum, col_pmax, col_psum,
                                         acc, cnt, out);
}